// Round 19
// baseline (126.973 us; speedup 1.0000x reference)
//
#include <hip/hip_runtime.h>
#include <hip/hip_bf16.h>
#include <stdint.h>

// Problem constants
#define NROWS 8192
#define FDIM 256
#define MCOLS 20000
#define NT32 625           // 20000 / 32, exact -> no tail masking
#define MSPLIT 16          // grid 16 x 32 = 512 blocks = 2/CU -> 2 waves/SIMD
#define NCLS 1000
#define LOG2E 1.44269504088896f
#define LN2   0.69314718055994f

// ws layout (bytes), total ~15.5 MB:
//   Mb2  bf16 memory, MFMA-fragment order : [0, 10240000)
//   Fb   bf16 box*5*log2e (row-major)     : [10240000, 14434304)
//   wsel weighted sel logits              : [14434304, 14467072)
//   pm   partial max [16][N]              : [14467072, 14991360)
//   ps   partial sum [16][N]              : [14991360, 15515648)
//   bpart block partials                  : [15515648, 15515776)
// NOTE: lse_gemm prefetches one tile past the end of Mb2 (harmless read into Fb).

typedef short short8 __attribute__((ext_vector_type(8)));
typedef float f32x16 __attribute__((ext_vector_type(16)));

__device__ __forceinline__ float ex2(float x) {   // raw v_exp_f32 (2^x)
    float r;
    asm("v_exp_f32 %0, %1" : "=v"(r) : "v"(x));
    return r;
}

__device__ __forceinline__ unsigned short f2bf(float x) {
    unsigned u = __float_as_uint(x);
    unsigned r = (u + 0x7FFFu + ((u >> 16) & 1u)) >> 16;   // RNE
    return (unsigned short)r;
}

// max of 16-vector via 3-ary nesting (fuses to v_max3_f32)
__device__ __forceinline__ float vmax16(f32x16 v) {
    float x0 = fmaxf(fmaxf(v[0],  v[1]),  v[2]);
    float x1 = fmaxf(fmaxf(v[3],  v[4]),  v[5]);
    float x2 = fmaxf(fmaxf(v[6],  v[7]),  v[8]);
    float x3 = fmaxf(fmaxf(v[9],  v[10]), v[11]);
    float x4 = fmaxf(fmaxf(v[12], v[13]), v[14]);
    float x5 = fmaxf(fmaxf(x0, x1), x2);
    float x6 = fmaxf(fmaxf(x3, x4), v[15]);
    return fmaxf(x5, x6);
}

// Fused prep + sel:
//   blocks [0,2500)    : Mb2 (fragment-order bf16 memory)
//   blocks [2500,4548) : Fb  (row-major bf16 box * 5*log2e)
//   blocks [4548,6596) : sel (weighted trace logits, fp32-exact)
__global__ void prep_kernel(const float* __restrict__ Mem, unsigned short* __restrict__ Mb2,
                            const float* __restrict__ F, unsigned short* __restrict__ Fb,
                            const int* __restrict__ gt, const int* __restrict__ trace,
                            float* __restrict__ wsel) {
    int b = blockIdx.x;
    if (b < 2500) {
        // Mb2: granule g = (t*16 + kk)*64 + s holds Mem[t*32 + (s&31)][kk*16 + (s>>5)*8 ..+8]
        int g = b * 256 + threadIdx.x;
        int s = g & 63, kk = (g >> 6) & 15, t = g >> 10;
        const float* src = Mem + (size_t)(t * 32 + (s & 31)) * FDIM + kk * 16 + (s >> 5) * 8;
        float4 v0 = ((const float4*)src)[0];
        float4 v1 = ((const float4*)src)[1];
        short8 w;
        w[0] = (short)f2bf(v0.x); w[1] = (short)f2bf(v0.y);
        w[2] = (short)f2bf(v0.z); w[3] = (short)f2bf(v0.w);
        w[4] = (short)f2bf(v1.x); w[5] = (short)f2bf(v1.y);
        w[6] = (short)f2bf(v1.z); w[7] = (short)f2bf(v1.w);
        *(short8*)(Mb2 + (size_t)g * 8) = w;
    } else if (b < 4548) {
        int idx = (b - 2500) * 256 + threadIdx.x;   // 2048 x 256 = 524288 float4s
        float4 v = ((const float4*)F)[idx];
        const float sc = 5.0f * LOG2E;
        ushort4 o;
        o.x = f2bf(v.x * sc); o.y = f2bf(v.y * sc);
        o.z = f2bf(v.z * sc); o.w = f2bf(v.w * sc);
        ((ushort4*)Fb)[idx] = o;
    } else {
        int lane = threadIdx.x & 63, wid = threadIdx.x >> 6;
        int i = (b - 4548) * 4 + wid;
        int label = gt[i];
        float w = 0.0f;
        if (label >= 0 && label < NCLS) {
            float4 fv = ((const float4*)(F + (size_t)i * FDIM))[lane];
            #pragma unroll
            for (int d = 1; d <= 3; ++d) {
                int tr = trace[label * 4 + d];
                float4 mv = ((const float4*)(Mem + (size_t)tr * FDIM))[lane];
                float dot = fv.x*mv.x + fv.y*mv.y + fv.z*mv.z + fv.w*mv.w;
                #pragma unroll
                for (int off = 32; off >= 1; off >>= 1) dot += __shfl_xor(dot, off, 64);
                w += (float)d * dot;
            }
        }
        if (lane == 0) wsel[i] = w * 5.0f;   // 1/T
    }
}

// Fused GEMM + online log2-sum-exp2 partials -- swapped-operand 32x32x16,
// 64 rows/wave, NO LDS / NO BARRIERS, MINIMAL PIPELINE STATE:
//   - single B register buffer b[16]: each fragment's next-tile load issues
//     right after its two MFMAs (WAR-safe in-register; ~2400 cyc latency
//     cover; vmcnt counting naturally waits on b[0] first next tile);
//   - single accumulator pair (accL/accH): cross-tile overlap now comes from
//     the SIBLING WAVE, not intra-wave scheduling.
// Budget: AGPR al/ah 128 + acc 32 = 160; VGPR b 64 + ~30 misc -> ~255 <= 256
// at __launch_bounds__(256,2) -> grid 16x32 = 512 blocks = 2 blocks/CU
// = 2 waves/SIMD: the SIMD scheduler interleaves wave A's softmax under
// wave B's MFMA chain (m114 mechanism) -- the overlap in-order issue at
// 1 wave/SIMD (R17/R18) could not produce.
__global__ __launch_bounds__(256, 2) void lse_gemm(
        const unsigned short* __restrict__ Fb, const unsigned short* __restrict__ Mb2,
        float* __restrict__ pm, float* __restrict__ ps) {
    const int split  = blockIdx.x;   // 0..15
    const int rowblk = blockIdx.y;   // 0..31
    const int tid  = threadIdx.x;
    const int lane = tid & 63, wid = tid >> 6;
    const int r0 = lane & 31;        // A-row within the 32-row half AND B-col
    const int hi = lane >> 5;        // k-slice half
    const int rowbase = rowblk * 256 + wid * 64;
    const int l16 = lane << 4;       // lane byte offset within a fragment

    // A fragments (Y-operand), two row-halves (al: +r0, ah: +32+r0)
    short8 al[16], ah[16];
    #pragma unroll
    for (int kk = 0; kk < 16; ++kk) {
        al[kk] = *(const short8*)(Fb + (size_t)(rowbase + r0)      * FDIM + kk * 16 + hi * 8);
        ah[kk] = *(const short8*)(Fb + (size_t)(rowbase + 32 + r0) * FDIM + kk * 16 + hi * 8);
    }

    // online state: one row per lane, per half
    float m0 = -3.0e38f, s0 = 0.0f, m1 = -3.0e38f, s1 = 0.0f;

    const int t0 = (split * NT32) / MSPLIT;
    const int t1 = ((split + 1) * NT32) / MSPLIT;   // 39-40 tiles per split

    // Prologue: load tile t0's 16 B-fragments (coalesced 1KB each).
    short8 b[16];
    {
        const char* src = (const char*)Mb2 + (size_t)t0 * 16384 + l16;
        #pragma unroll
        for (int kk = 0; kk < 16; ++kk)
            b[kk] = *(const short8*)(src + kk * 1024);
    }

    for (int t = t0; t < t1; ++t) {
        // next-tile base (last iteration over-reads 16KB into Fb -- harmless)
        const char* nsrc = (const char*)Mb2 + (size_t)(t + 1) * 16384 + l16;
        f32x16 accL = {0,0,0,0,0,0,0,0,0,0,0,0,0,0,0,0};
        f32x16 accH = {0,0,0,0,0,0,0,0,0,0,0,0,0,0,0,0};
        #pragma unroll
        for (int kk = 0; kk < 16; ++kk) {
            short8 bb = b[kk];
            accL = __builtin_amdgcn_mfma_f32_32x32x16_bf16(bb, al[kk], accL, 0, 0, 0);
            accH = __builtin_amdgcn_mfma_f32_32x32x16_bf16(bb, ah[kk], accH, 0, 0, 0);
            b[kk] = *(const short8*)(nsrc + kk * 1024);   // prefetch next tile
        }
        {   // softmax, half L
            float nm = fmaxf(vmax16(accL), m0);
            float p0 = 0.f, p1 = 0.f;
            #pragma unroll
            for (int i = 0; i < 16; i += 2) {
                p0 += ex2(accL[i] - nm); p1 += ex2(accL[i + 1] - nm);
            }
            s0 = fmaf(s0, ex2(m0 - nm), p0 + p1); m0 = nm;
        }
        {   // softmax, half H
            float nm = fmaxf(vmax16(accH), m1);
            float p0 = 0.f, p1 = 0.f;
            #pragma unroll
            for (int i = 0; i < 16; i += 2) {
                p0 += ex2(accH[i] - nm); p1 += ex2(accH[i + 1] - nm);
            }
            s1 = fmaf(s1, ex2(m1 - nm), p0 + p1); m1 = nm;
        }
    }

    // Combine the two k-slice halves: lane l and l^32 hold the same row's two
    // 16-col subsets (for both row-halves).
    {
        float om = __shfl_xor(m0, 32, 64);
        float os = __shfl_xor(s0, 32, 64);
        float nm = fmaxf(m0, om);
        float sf = fmaf(s0, ex2(m0 - nm), os * ex2(om - nm));
        if (lane < 32) {
            pm[split * NROWS + rowbase + lane] = nm;
            ps[split * NROWS + rowbase + lane] = sf;
        }
    }
    {
        float om = __shfl_xor(m1, 32, 64);
        float os = __shfl_xor(s1, 32, 64);
        float nm = fmaxf(m1, om);
        float sf = fmaf(s1, ex2(m1 - nm), os * ex2(om - nm));
        if (lane < 32) {
            pm[split * NROWS + rowbase + 32 + lane] = nm;
            ps[split * NROWS + rowbase + 32 + lane] = sf;
        }
    }
}

__global__ void finalize_kernel(const int* __restrict__ gt, const float* __restrict__ wsel,
                                const float* __restrict__ pm, const float* __restrict__ ps,
                                float* __restrict__ bpart) {
    int tid = threadIdx.x;
    int i = blockIdx.x * 256 + tid;
    float mv[MSPLIT];
    float M = -3.0e38f;
    #pragma unroll
    for (int k = 0; k < MSPLIT; ++k) { mv[k] = pm[k * NROWS + i]; M = fmaxf(M, mv[k]); }
    float S = 0.0f;
    #pragma unroll
    for (int k = 0; k < MSPLIT; ++k) S += ps[k * NROWS + i] * ex2(mv[k] - M);
    float lse = (M + __log2f(S)) * LN2;   // back to natural-log domain
    int label = gt[i];
    float per = (label >= 0 && label < NCLS) ? (lse - wsel[i] * (1.0f / 6.0f)) : 0.0f;
    #pragma unroll
    for (int off = 32; off >= 1; off >>= 1) per += __shfl_xor(per, off, 64);
    __shared__ float red[4];
    int lane = tid & 63, wid = tid >> 6;
    if (lane == 0) red[wid] = per;
    __syncthreads();
    if (tid == 0) bpart[blockIdx.x] = red[0] + red[1] + red[2] + red[3];
}

__global__ void sum_kernel(const float* __restrict__ bpart, float* __restrict__ out) {
    int tid = threadIdx.x;
    float v = (tid < 32) ? bpart[tid] : 0.0f;
    #pragma unroll
    for (int off = 32; off >= 1; off >>= 1) v += __shfl_xor(v, off, 64);
    if (tid == 0) out[0] = 0.001f * v;
}

extern "C" void kernel_launch(void* const* d_in, const int* in_sizes, int n_in,
                              void* d_out, int out_size, void* d_ws, size_t ws_size,
                              hipStream_t stream) {
    const int*   gt    = (const int*)d_in[0];
    const float* F     = (const float*)d_in[1];
    const float* Mem   = (const float*)d_in[2];
    const int*   trace = (const int*)d_in[3];
    float* out = (float*)d_out;

    char* w = (char*)d_ws;
    unsigned short* Mb2 = (unsigned short*)w;
    unsigned short* Fb  = (unsigned short*)(w + 10240000);
    float* wsel  = (float*)(w + 14434304);
    float* pm    = (float*)(w + 14467072);
    float* ps    = (float*)(w + 14991360);
    float* bpart = (float*)(w + 15515648);

    prep_kernel<<<dim3(6596), dim3(256), 0, stream>>>(Mem, Mb2, F, Fb, gt, trace, wsel);
    lse_gemm<<<dim3(MSPLIT, NROWS / 256), dim3(256), 0, stream>>>(Fb, Mb2, pm, ps);
    finalize_kernel<<<dim3(NROWS / 256), dim3(256), 0, stream>>>(gt, wsel, pm, ps, bpart);
    sum_kernel<<<dim3(1), dim3(64), 0, stream>>>(bpart, out);
}

// Round 21
// 108.184 us; speedup vs baseline: 1.1737x; 1.1737x over previous
//
#include <hip/hip_runtime.h>
#include <hip/hip_bf16.h>
#include <stdint.h>

// Problem constants
#define NROWS 8192
#define FDIM 256
#define MCOLS 20000
#define NT32 625           // 20000 / 32, exact -> no tail masking
#define MSPLIT 8           // grid 8 x 32 = 256 blocks = 1/CU; split == XCD id
#define NCLS 1000
#define LOG2E 1.44269504088896f
#define LN2   0.69314718055994f

// ws layout (bytes), total ~15.5 MB:
//   Mb2  bf16 memory, MFMA-fragment order : [0, 10240000)
//   Fb   bf16 box*5*log2e (row-major)     : [10240000, 14434304)
//   wsel weighted sel logits              : [14434304, 14467072)
//   pm   partial max [8][N]               : [14467072, 14991360)
//   ps   partial sum [8][N]               : [14991360, 15515648)
//   bpart block partials                  : [15515648, 15515776)

typedef short short8 __attribute__((ext_vector_type(8)));
typedef float f32x16 __attribute__((ext_vector_type(16)));

__device__ __forceinline__ float ex2(float x) {   // raw v_exp_f32 (2^x)
    float r;
    asm("v_exp_f32 %0, %1" : "=v"(r) : "v"(x));
    return r;
}

__device__ __forceinline__ unsigned short f2bf(float x) {
    unsigned u = __float_as_uint(x);
    unsigned r = (u + 0x7FFFu + ((u >> 16) & 1u)) >> 16;   // RNE
    return (unsigned short)r;
}

// max of 16-vector via 3-ary nesting (fuses to v_max3_f32)
__device__ __forceinline__ float vmax16(f32x16 v) {
    float x0 = fmaxf(fmaxf(v[0],  v[1]),  v[2]);
    float x1 = fmaxf(fmaxf(v[3],  v[4]),  v[5]);
    float x2 = fmaxf(fmaxf(v[6],  v[7]),  v[8]);
    float x3 = fmaxf(fmaxf(v[9],  v[10]), v[11]);
    float x4 = fmaxf(fmaxf(v[12], v[13]), v[14]);
    float x5 = fmaxf(fmaxf(x0, x1), x2);
    float x6 = fmaxf(fmaxf(x3, x4), v[15]);
    return fmaxf(x5, x6);
}

// Fused prep + sel:
//   blocks [0,2500)    : Mb2 (fragment-order bf16 memory)
//   blocks [2500,4548) : Fb  (row-major bf16 box * 5*log2e)
//   blocks [4548,6596) : sel (weighted trace logits, fp32-exact)
__global__ void prep_kernel(const float* __restrict__ Mem, unsigned short* __restrict__ Mb2,
                            const float* __restrict__ F, unsigned short* __restrict__ Fb,
                            const int* __restrict__ gt, const int* __restrict__ trace,
                            float* __restrict__ wsel) {
    int b = blockIdx.x;
    if (b < 2500) {
        // Mb2: granule g = (t*16 + kk)*64 + s holds Mem[t*32 + (s&31)][kk*16 + (s>>5)*8 ..+8]
        int g = b * 256 + threadIdx.x;
        int s = g & 63, kk = (g >> 6) & 15, t = g >> 10;
        const float* src = Mem + (size_t)(t * 32 + (s & 31)) * FDIM + kk * 16 + (s >> 5) * 8;
        float4 v0 = ((const float4*)src)[0];
        float4 v1 = ((const float4*)src)[1];
        short8 w;
        w[0] = (short)f2bf(v0.x); w[1] = (short)f2bf(v0.y);
        w[2] = (short)f2bf(v0.z); w[3] = (short)f2bf(v0.w);
        w[4] = (short)f2bf(v1.x); w[5] = (short)f2bf(v1.y);
        w[6] = (short)f2bf(v1.z); w[7] = (short)f2bf(v1.w);
        *(short8*)(Mb2 + (size_t)g * 8) = w;
    } else if (b < 4548) {
        int idx = (b - 2500) * 256 + threadIdx.x;   // 2048 x 256 = 524288 float4s
        float4 v = ((const float4*)F)[idx];
        const float sc = 5.0f * LOG2E;
        ushort4 o;
        o.x = f2bf(v.x * sc); o.y = f2bf(v.y * sc);
        o.z = f2bf(v.z * sc); o.w = f2bf(v.w * sc);
        ((ushort4*)Fb)[idx] = o;
    } else {
        int lane = threadIdx.x & 63, wid = threadIdx.x >> 6;
        int i = (b - 4548) * 4 + wid;
        int label = gt[i];
        float w = 0.0f;
        if (label >= 0 && label < NCLS) {
            float4 fv = ((const float4*)(F + (size_t)i * FDIM))[lane];
            #pragma unroll
            for (int d = 1; d <= 3; ++d) {
                int tr = trace[label * 4 + d];
                float4 mv = ((const float4*)(Mem + (size_t)tr * FDIM))[lane];
                float dot = fv.x*mv.x + fv.y*mv.y + fv.z*mv.z + fv.w*mv.w;
                #pragma unroll
                for (int off = 32; off >= 1; off >>= 1) dot += __shfl_xor(dot, off, 64);
                w += (float)d * dot;
            }
        }
        if (lane == 0) wsel[i] = w * 5.0f;   // 1/T
    }
}

// Fused GEMM + online log2-sum-exp2 partials -- swapped-operand 32x32x16,
// 64 rows/wave, NO LDS / NO BARRIERS (R18 base), plus:
//   (1) FOUR MFMA chains per tile (even/odd kk x L/H): same-chain reuse gap
//       = 4 MFMA issues (~130 pipe cyc) -> dependent-MFMA stalls gone;
//   (2) softmax of tile t-1 split into 8 pieces PINNED between MFMA pairs
//       with sched_barrier(0). CORRECTNESS FIX vs R20: chains L0/L1 (and
//       H0/H1) are PARTIAL SUMS of the same logits -> piece 0 adds them
//       elementwise (accL0 += accL1) BEFORE max/exp (R13's exact identity).
// Registers: acc 8x16=128 + al/ah 128 (AGPR-class) + b0/b1 128 VGPR + ~50
// misc => ~434 < 512 unified at waves_per_eu(1,1). Grid 8x32 = 256 = 1/CU.
__global__ __attribute__((amdgpu_flat_work_group_size(256, 256), amdgpu_waves_per_eu(1, 1)))
void lse_gemm(
        const unsigned short* __restrict__ Fb, const unsigned short* __restrict__ Mb2,
        float* __restrict__ pm, float* __restrict__ ps) {
    const int split  = blockIdx.x;   // 0..7 == XCD id
    const int rowblk = blockIdx.y;   // 0..31
    const int tid  = threadIdx.x;
    const int lane = tid & 63, wid = tid >> 6;
    const int r0 = lane & 31;        // A-row within the 32-row half AND B-col
    const int hi = lane >> 5;        // k-slice half
    const int rowbase = rowblk * 256 + wid * 64;
    const int l16 = lane << 4;       // lane byte offset within a fragment

    // A fragments (Y-operand), two row-halves (al: +r0, ah: +32+r0)
    short8 al[16], ah[16];
    #pragma unroll
    for (int kk = 0; kk < 16; ++kk) {
        al[kk] = *(const short8*)(Fb + (size_t)(rowbase + r0)      * FDIM + kk * 16 + hi * 8);
        ah[kk] = *(const short8*)(Fb + (size_t)(rowbase + 32 + r0) * FDIM + kk * 16 + hi * 8);
    }

    // online state: one row per lane, per half
    float m0 = -3.0e38f, s0 = 0.0f, m1 = -3.0e38f, s1 = 0.0f;
    // softmax pipeline temps (live across interleave pieces)
    float nmL, nmH, q0, q1, q2, q3, r0x, r1x, r2x, r3x;
    // 4 chains x A/B tile-double-buffer = 8 accumulators (named, static)
    f32x16 accAL0, accAL1, accAH0, accAH1, accBL0, accBL1, accBH0, accBH1;
    short8 b0[16], b1[16];

    const int t0 = (split * NT32) / MSPLIT;
    const int t1 = ((split + 1) * NT32) / MSPLIT;   // 78-79 tiles per split

#define LOADB(BB, t)                                                               \
    do {                                                                           \
        const char* srcT_ = (const char*)Mb2 + (size_t)(t) * 16384 + l16;          \
        _Pragma("unroll")                                                          \
        for (int kk = 0; kk < 16; ++kk)                                            \
            BB[kk] = *(const short8*)(srcT_ + kk * 1024);                          \
    } while (0)

#define SB __builtin_amdgcn_sched_barrier(0);

    // One even-kk step (chain 0) and one odd-kk step (chain 1):
#define MFMA_E(BB, CUR, KK)                                                        \
    acc##CUR##L0 = __builtin_amdgcn_mfma_f32_32x32x16_bf16(BB[KK], al[KK], acc##CUR##L0, 0, 0, 0); \
    acc##CUR##H0 = __builtin_amdgcn_mfma_f32_32x32x16_bf16(BB[KK], ah[KK], acc##CUR##H0, 0, 0, 0);
#define MFMA_O(BB, CUR, KK)                                                        \
    acc##CUR##L1 = __builtin_amdgcn_mfma_f32_32x32x16_bf16(BB[KK], al[KK], acc##CUR##L1, 0, 0, 0); \
    acc##CUR##H1 = __builtin_amdgcn_mfma_f32_32x32x16_bf16(BB[KK], ah[KK], acc##CUR##H1, 0, 0, 0);

    // Softmax pieces over PRV's accs. Chains are PARTIAL SUMS: combine first.
#define SM0(P) acc##P##L0 = acc##P##L0 + acc##P##L1;            /* 16 v_add  */
#define SM1(P) nmL = fmaxf(vmax16(acc##P##L0), m0);             /* max tree  */ \
               q0 = q1 = q2 = q3 = 0.f;
#define SM2(P)                                                                     \
    q0 += ex2(acc##P##L0[0] - nmL); q1 += ex2(acc##P##L0[1] - nmL);                \
    q2 += ex2(acc##P##L0[2] - nmL); q3 += ex2(acc##P##L0[3] - nmL);                \
    q0 += ex2(acc##P##L0[4] - nmL); q1 += ex2(acc##P##L0[5] - nmL);                \
    q2 += ex2(acc##P##L0[6] - nmL); q3 += ex2(acc##P##L0[7] - nmL);
#define SM3(P)                                                                     \
    q0 += ex2(acc##P##L0[8]  - nmL); q1 += ex2(acc##P##L0[9]  - nmL);              \
    q2 += ex2(acc##P##L0[10] - nmL); q3 += ex2(acc##P##L0[11] - nmL);              \
    q0 += ex2(acc##P##L0[12] - nmL); q1 += ex2(acc##P##L0[13] - nmL);              \
    q2 += ex2(acc##P##L0[14] - nmL); q3 += ex2(acc##P##L0[15] - nmL);              \
    s0 = fmaf(s0, ex2(m0 - nmL), (q0 + q1) + (q2 + q3)); m0 = nmL;
#define SM4(P) acc##P##H0 = acc##P##H0 + acc##P##H1;
#define SM5(P) nmH = fmaxf(vmax16(acc##P##H0), m1);                                \
               r0x = r1x = r2x = r3x = 0.f;
#define SM6(P)                                                                     \
    r0x += ex2(acc##P##H0[0] - nmH); r1x += ex2(acc##P##H0[1] - nmH);              \
    r2x += ex2(acc##P##H0[2] - nmH); r3x += ex2(acc##P##H0[3] - nmH);              \
    r0x += ex2(acc##P##H0[4] - nmH); r1x += ex2(acc##P##H0[5] - nmH);              \
    r2x += ex2(acc##P##H0[6] - nmH); r3x += ex2(acc##P##H0[7] - nmH);
#define SM7(P)                                                                     \
    r0x += ex2(acc##P##H0[8]  - nmH); r1x += ex2(acc##P##H0[9]  - nmH);            \
    r2x += ex2(acc##P##H0[10] - nmH); r3x += ex2(acc##P##H0[11] - nmH);            \
    r0x += ex2(acc##P##H0[12] - nmH); r1x += ex2(acc##P##H0[13] - nmH);            \
    r2x += ex2(acc##P##H0[14] - nmH); r3x += ex2(acc##P##H0[15] - nmH);            \
    s1 = fmaf(s1, ex2(m1 - nmH), (r0x + r1x) + (r2x + r3x)); m1 = nmH;

#define ZERO4(CUR)                                                                 \
    { f32x16 z_ = {0,0,0,0,0,0,0,0,0,0,0,0,0,0,0,0};                               \
      acc##CUR##L0 = z_; acc##CUR##L1 = z_; acc##CUR##H0 = z_; acc##CUR##H1 = z_; }

    // MFMA(tile in BB -> CUR) with softmax(PRV) pinned between MFMA pairs.
#define PIPE(BB, CUR, PRV)                                                         \
    do {                                                                           \
        ZERO4(CUR)                                                                 \
        MFMA_E(BB, CUR, 0)  MFMA_O(BB, CUR, 1)  SM0(PRV) SB                        \
        MFMA_E(BB, CUR, 2)  MFMA_O(BB, CUR, 3)  SM1(PRV) SB                        \
        MFMA_E(BB, CUR, 4)  MFMA_O(BB, CUR, 5)  SM2(PRV) SB                        \
        MFMA_E(BB, CUR, 6)  MFMA_O(BB, CUR, 7)  SM3(PRV) SB                        \
        MFMA_E(BB, CUR, 8)  MFMA_O(BB, CUR, 9)  SM4(PRV) SB                        \
        MFMA_E(BB, CUR, 10) MFMA_O(BB, CUR, 11) SM5(PRV) SB                        \
        MFMA_E(BB, CUR, 12) MFMA_O(BB, CUR, 13) SM6(PRV) SB                        \
        MFMA_E(BB, CUR, 14) MFMA_O(BB, CUR, 15) SM7(PRV)                           \
    } while (0)

#define MFMA_ONLY(BB, CUR)                                                         \
    do {                                                                           \
        ZERO4(CUR)                                                                 \
        _Pragma("unroll")                                                          \
        for (int kk = 0; kk < 16; kk += 2) { MFMA_E(BB, CUR, kk) MFMA_O(BB, CUR, kk + 1) } \
    } while (0)

#define SM_FULL(P) do { SM0(P) SM1(P) SM2(P) SM3(P) SM4(P) SM5(P) SM6(P) SM7(P) } while (0)

    // Prologue: fill both B buffers, compute tile t0 -> accA.
    LOADB(b0, t0);
    LOADB(b1, t0 + 1);         // nt >= 78, always exists
    MFMA_ONLY(b0, A);

    int t = t0 + 1;            // tile t is in b1 at loop head
    while (t + 1 < t1) {
        LOADB(b0, t + 1);      // prefetch next tile into the freed buffer
        PIPE(b1, B, A);        // tile t -> accB; softmax(tile t-1 = accA)
        if (t + 2 < t1) LOADB(b1, t + 2);
        PIPE(b0, A, B);        // tile t+1 -> accA; softmax(tile t = accB)
        t += 2;
    }
    if (t < t1) {              // one tile left, resident in b1
        PIPE(b1, B, A);
        SM_FULL(B);
    } else {
        SM_FULL(A);
    }

#undef SM_FULL
#undef MFMA_ONLY
#undef PIPE
#undef ZERO4
#undef SM7
#undef SM6
#undef SM5
#undef SM4
#undef SM3
#undef SM2
#undef SM1
#undef SM0
#undef MFMA_O
#undef MFMA_E
#undef SB
#undef LOADB

    // Combine the two k-slice halves: lane l and l^32 hold the same row's two
    // 16-col subsets (for both row-halves).
    {
        float om = __shfl_xor(m0, 32, 64);
        float os = __shfl_xor(s0, 32, 64);
        float nm = fmaxf(m0, om);
        float sf = fmaf(s0, ex2(m0 - nm), os * ex2(om - nm));
        if (lane < 32) {
            pm[split * NROWS + rowbase + lane] = nm;
            ps[split * NROWS + rowbase + lane] = sf;
        }
    }
    {
        float om = __shfl_xor(m1, 32, 64);
        float os = __shfl_xor(s1, 32, 64);
        float nm = fmaxf(m1, om);
        float sf = fmaf(s1, ex2(m1 - nm), os * ex2(om - nm));
        if (lane < 32) {
            pm[split * NROWS + rowbase + 32 + lane] = nm;
            ps[split * NROWS + rowbase + 32 + lane] = sf;
        }
    }
}

__global__ void finalize_kernel(const int* __restrict__ gt, const float* __restrict__ wsel,
                                const float* __restrict__ pm, const float* __restrict__ ps,
                                float* __restrict__ bpart) {
    int tid = threadIdx.x;
    int i = blockIdx.x * 256 + tid;
    float mv[MSPLIT];
    float M = -3.0e38f;
    #pragma unroll
    for (int k = 0; k < MSPLIT; ++k) { mv[k] = pm[k * NROWS + i]; M = fmaxf(M, mv[k]); }
    float S = 0.0f;
    #pragma unroll
    for (int k = 0; k < MSPLIT; ++k) S += ps[k * NROWS + i] * ex2(mv[k] - M);
    float lse = (M + __log2f(S)) * LN2;   // back to natural-log domain
    int label = gt[i];
    float per = (label >= 0 && label < NCLS) ? (lse - wsel[i] * (1.0f / 6.0f)) : 0.0f;
    #pragma unroll
    for (int off = 32; off >= 1; off >>= 1) per += __shfl_xor(per, off, 64);
    __shared__ float red[4];
    int lane = tid & 63, wid = tid >> 6;
    if (lane == 0) red[wid] = per;
    __syncthreads();
    if (tid == 0) bpart[blockIdx.x] = red[0] + red[1] + red[2] + red[3];
}

__global__ void sum_kernel(const float* __restrict__ bpart, float* __restrict__ out) {
    int tid = threadIdx.x;
    float v = (tid < 32) ? bpart[tid] : 0.0f;
    #pragma unroll
    for (int off = 32; off >= 1; off >>= 1) v += __shfl_xor(v, off, 64);
    if (tid == 0) out[0] = 0.001f * v;
}

extern "C" void kernel_launch(void* const* d_in, const int* in_sizes, int n_in,
                              void* d_out, int out_size, void* d_ws, size_t ws_size,
                              hipStream_t stream) {
    const int*   gt    = (const int*)d_in[0];
    const float* F     = (const float*)d_in[1];
    const float* Mem   = (const float*)d_in[2];
    const int*   trace = (const int*)d_in[3];
    float* out = (float*)d_out;

    char* w = (char*)d_ws;
    unsigned short* Mb2 = (unsigned short*)w;
    unsigned short* Fb  = (unsigned short*)(w + 10240000);
    float* wsel  = (float*)(w + 14434304);
    float* pm    = (float*)(w + 14467072);
    float* ps    = (float*)(w + 14991360);
    float* bpart = (float*)(w + 15515648);

    prep_kernel<<<dim3(6596), dim3(256), 0, stream>>>(Mem, Mb2, F, Fb, gt, trace, wsel);
    lse_gemm<<<dim3(MSPLIT, NROWS / 256), dim3(256), 0, stream>>>(Fb, Mb2, pm, ps);
    finalize_kernel<<<dim3(NROWS / 256), dim3(256), 0, stream>>>(gt, wsel, pm, ps, bpart);
    sum_kernel<<<dim3(1), dim3(64), 0, stream>>>(bpart, out);
}

// Round 22
// 104.968 us; speedup vs baseline: 1.2096x; 1.0306x over previous
//
#include <hip/hip_runtime.h>
#include <hip/hip_bf16.h>
#include <stdint.h>

// Problem constants
#define NROWS 8192
#define FDIM 256
#define MCOLS 20000
#define NT32 625           // 20000 / 32, exact -> no tail masking
#define MSPLIT 8           // grid 8 x 32 = 256 blocks = 1/CU; split == XCD id
#define NCLS 1000
#define LOG2E 1.44269504088896f
#define LN2   0.69314718055994f

// ws layout (bytes), total ~15.5 MB:
//   Mb2  bf16 memory, MFMA-fragment order : [0, 10240000)
//   Fb   bf16 box*5*log2e (row-major)     : [10240000, 14434304)
//   wsel weighted sel logits              : [14434304, 14467072)
//   pm   partial max [8][N]               : [14467072, 14991360)
//   ps   partial sum [8][N]               : [14991360, 15515648)
//   bpart block partials                  : [15515648, 15515776)

typedef short short8 __attribute__((ext_vector_type(8)));
typedef float f32x16 __attribute__((ext_vector_type(16)));

__device__ __forceinline__ float ex2(float x) {   // raw v_exp_f32 (2^x)
    float r;
    asm("v_exp_f32 %0, %1" : "=v"(r) : "v"(x));
    return r;
}

__device__ __forceinline__ unsigned short f2bf(float x) {
    unsigned u = __float_as_uint(x);
    unsigned r = (u + 0x7FFFu + ((u >> 16) & 1u)) >> 16;   // RNE
    return (unsigned short)r;
}

// max of 16-vector via 3-ary nesting (fuses to v_max3_f32)
__device__ __forceinline__ float vmax16(f32x16 v) {
    float x0 = fmaxf(fmaxf(v[0],  v[1]),  v[2]);
    float x1 = fmaxf(fmaxf(v[3],  v[4]),  v[5]);
    float x2 = fmaxf(fmaxf(v[6],  v[7]),  v[8]);
    float x3 = fmaxf(fmaxf(v[9],  v[10]), v[11]);
    float x4 = fmaxf(fmaxf(v[12], v[13]), v[14]);
    float x5 = fmaxf(fmaxf(x0, x1), x2);
    float x6 = fmaxf(fmaxf(x3, x4), v[15]);
    return fmaxf(x5, x6);
}

// Fused prep + sel:
//   blocks [0,2500)    : Mb2 (fragment-order bf16 memory)
//   blocks [2500,4548) : Fb  (row-major bf16 box * 5*log2e)
//   blocks [4548,6596) : sel (weighted trace logits, fp32-exact)
__global__ void prep_kernel(const float* __restrict__ Mem, unsigned short* __restrict__ Mb2,
                            const float* __restrict__ F, unsigned short* __restrict__ Fb,
                            const int* __restrict__ gt, const int* __restrict__ trace,
                            float* __restrict__ wsel) {
    int b = blockIdx.x;
    if (b < 2500) {
        // Mb2: granule g = (t*16 + kk)*64 + s holds Mem[t*32 + (s&31)][kk*16 + (s>>5)*8 ..+8]
        int g = b * 256 + threadIdx.x;
        int s = g & 63, kk = (g >> 6) & 15, t = g >> 10;
        const float* src = Mem + (size_t)(t * 32 + (s & 31)) * FDIM + kk * 16 + (s >> 5) * 8;
        float4 v0 = ((const float4*)src)[0];
        float4 v1 = ((const float4*)src)[1];
        short8 w;
        w[0] = (short)f2bf(v0.x); w[1] = (short)f2bf(v0.y);
        w[2] = (short)f2bf(v0.z); w[3] = (short)f2bf(v0.w);
        w[4] = (short)f2bf(v1.x); w[5] = (short)f2bf(v1.y);
        w[6] = (short)f2bf(v1.z); w[7] = (short)f2bf(v1.w);
        *(short8*)(Mb2 + (size_t)g * 8) = w;
    } else if (b < 4548) {
        int idx = (b - 2500) * 256 + threadIdx.x;   // 2048 x 256 = 524288 float4s
        float4 v = ((const float4*)F)[idx];
        const float sc = 5.0f * LOG2E;
        ushort4 o;
        o.x = f2bf(v.x * sc); o.y = f2bf(v.y * sc);
        o.z = f2bf(v.z * sc); o.w = f2bf(v.w * sc);
        ((ushort4*)Fb)[idx] = o;
    } else {
        int lane = threadIdx.x & 63, wid = threadIdx.x >> 6;
        int i = (b - 4548) * 4 + wid;
        int label = gt[i];
        float w = 0.0f;
        if (label >= 0 && label < NCLS) {
            float4 fv = ((const float4*)(F + (size_t)i * FDIM))[lane];
            #pragma unroll
            for (int d = 1; d <= 3; ++d) {
                int tr = trace[label * 4 + d];
                float4 mv = ((const float4*)(Mem + (size_t)tr * FDIM))[lane];
                float dot = fv.x*mv.x + fv.y*mv.y + fv.z*mv.z + fv.w*mv.w;
                #pragma unroll
                for (int off = 32; off >= 1; off >>= 1) dot += __shfl_xor(dot, off, 64);
                w += (float)d * dot;
            }
        }
        if (lane == 0) wsel[i] = w * 5.0f;   // 1/T
    }
}

// Fused GEMM + online log2-sum-exp2 partials -- swapped-operand 32x32x16,
// 64 rows/wave, NO LDS / NO BARRIERS (R18 base, 80.3us) with ONE isolated
// change: FOUR independent MFMA chains (even/odd kk x L/H). Dep-distance
// per chain = 4 MFMA issues (~128 pipe cyc) -- covers the hypothesized
// ~128-cyc dependent-MFMA latency that capped R18's MFMA section at half
// rate. Chains are exact partial sums; combined with elementwise adds
// BEFORE softmax. NO sched_barrier pinning (R21 proved it hurts) -- the
// scheduler handled R18 well; give it the same freedom with more ILP.
// Registers: acc 128 + al/ah 128 (AGPR-class) + b0/b1 128 VGPR + ~50 misc
// => ~456 < 512 unified at waves_per_eu(1,1). Grid 8x32 = 256 = 1/CU.
__global__ __attribute__((amdgpu_flat_work_group_size(256, 256), amdgpu_waves_per_eu(1, 1)))
void lse_gemm(
        const unsigned short* __restrict__ Fb, const unsigned short* __restrict__ Mb2,
        float* __restrict__ pm, float* __restrict__ ps) {
    const int split  = blockIdx.x;   // 0..7 == XCD id
    const int rowblk = blockIdx.y;   // 0..31
    const int tid  = threadIdx.x;
    const int lane = tid & 63, wid = tid >> 6;
    const int r0 = lane & 31;        // A-row within the 32-row half AND B-col
    const int hi = lane >> 5;        // k-slice half
    const int rowbase = rowblk * 256 + wid * 64;
    const int l16 = lane << 4;       // lane byte offset within a fragment

    // A fragments (Y-operand), two row-halves (al: +r0, ah: +32+r0)
    short8 al[16], ah[16];
    #pragma unroll
    for (int kk = 0; kk < 16; ++kk) {
        al[kk] = *(const short8*)(Fb + (size_t)(rowbase + r0)      * FDIM + kk * 16 + hi * 8);
        ah[kk] = *(const short8*)(Fb + (size_t)(rowbase + 32 + r0) * FDIM + kk * 16 + hi * 8);
    }

    // online state: one row per lane, per half
    float m0 = -3.0e38f, s0 = 0.0f, m1 = -3.0e38f, s1 = 0.0f;
    // 4 chains x A/B tile-double-buffer = 8 accumulators (named, static)
    f32x16 accAL0, accAL1, accAH0, accAH1, accBL0, accBL1, accBH0, accBH1;
    short8 b0[16], b1[16];

    const int t0 = (split * NT32) / MSPLIT;
    const int t1 = ((split + 1) * NT32) / MSPLIT;   // 78-79 tiles per split

#define LOADB(BB, t)                                                               \
    do {                                                                           \
        const char* srcT_ = (const char*)Mb2 + (size_t)(t) * 16384 + l16;          \
        _Pragma("unroll")                                                          \
        for (int kk = 0; kk < 16; ++kk)                                            \
            BB[kk] = *(const short8*)(srcT_ + kk * 1024);                          \
    } while (0)

    // 4-chain MFMA over one tile's 16 fragments (even->L0/H0, odd->L1/H1).
#define MFMA_TILE(BB, CUR)                                                         \
    do {                                                                           \
        f32x16 z_ = {0,0,0,0,0,0,0,0,0,0,0,0,0,0,0,0};                             \
        acc##CUR##L0 = z_; acc##CUR##L1 = z_; acc##CUR##H0 = z_; acc##CUR##H1 = z_;\
        _Pragma("unroll")                                                          \
        for (int kk = 0; kk < 16; kk += 2) {                                       \
            acc##CUR##L0 = __builtin_amdgcn_mfma_f32_32x32x16_bf16(BB[kk],     al[kk],     acc##CUR##L0, 0, 0, 0); \
            acc##CUR##H0 = __builtin_amdgcn_mfma_f32_32x32x16_bf16(BB[kk],     ah[kk],     acc##CUR##H0, 0, 0, 0); \
            acc##CUR##L1 = __builtin_amdgcn_mfma_f32_32x32x16_bf16(BB[kk + 1], al[kk + 1], acc##CUR##L1, 0, 0, 0); \
            acc##CUR##H1 = __builtin_amdgcn_mfma_f32_32x32x16_bf16(BB[kk + 1], ah[kk + 1], acc##CUR##H1, 0, 0, 0); \
        }                                                                          \
    } while (0)

    // Combine partial-sum chains (exact) then R18's softmax.
#define SOFTMAX(P)                                                                 \
    do {                                                                           \
        acc##P##L0 = acc##P##L0 + acc##P##L1;                                      \
        acc##P##H0 = acc##P##H0 + acc##P##H1;                                      \
        {                                                                          \
            float nm = fmaxf(vmax16(acc##P##L0), m0);                              \
            float p0 = 0.f, p1 = 0.f;                                              \
            _Pragma("unroll")                                                      \
            for (int i = 0; i < 16; i += 2) {                                      \
                p0 += ex2(acc##P##L0[i] - nm); p1 += ex2(acc##P##L0[i + 1] - nm);  \
            }                                                                      \
            s0 = fmaf(s0, ex2(m0 - nm), p0 + p1); m0 = nm;                         \
        }                                                                          \
        {                                                                          \
            float nm = fmaxf(vmax16(acc##P##H0), m1);                              \
            float p0 = 0.f, p1 = 0.f;                                              \
            _Pragma("unroll")                                                      \
            for (int i = 0; i < 16; i += 2) {                                      \
                p0 += ex2(acc##P##H0[i] - nm); p1 += ex2(acc##P##H0[i + 1] - nm);  \
            }                                                                      \
            s1 = fmaf(s1, ex2(m1 - nm), p0 + p1); m1 = nm;                         \
        }                                                                          \
    } while (0)

    // Prologue: fill both B buffers, compute tile t0 -> accA.
    LOADB(b0, t0);
    LOADB(b1, t0 + 1);         // nt >= 78, always exists
    MFMA_TILE(b0, A);

    int t = t0 + 1;            // tile t is in b1 at loop head
    while (t + 1 < t1) {
        LOADB(b0, t + 1);      // prefetch next tile into the freed buffer
        MFMA_TILE(b1, B);      // tile t -> accB
        SOFTMAX(A);            // softmax of tile t-1 (independent of accB MFMAs)
        if (t + 2 < t1) LOADB(b1, t + 2);
        MFMA_TILE(b0, A);      // tile t+1 -> accA
        SOFTMAX(B);            // softmax of tile t
        t += 2;
    }
    if (t < t1) {              // one tile left, resident in b1
        MFMA_TILE(b1, B);
        SOFTMAX(A);
        SOFTMAX(B);
    } else {
        SOFTMAX(A);
    }

#undef SOFTMAX
#undef MFMA_TILE
#undef LOADB

    // Combine the two k-slice halves: lane l and l^32 hold the same row's two
    // 16-col subsets (for both row-halves).
    {
        float om = __shfl_xor(m0, 32, 64);
        float os = __shfl_xor(s0, 32, 64);
        float nm = fmaxf(m0, om);
        float sf = fmaf(s0, ex2(m0 - nm), os * ex2(om - nm));
        if (lane < 32) {
            pm[split * NROWS + rowbase + lane] = nm;
            ps[split * NROWS + rowbase + lane] = sf;
        }
    }
    {
        float om = __shfl_xor(m1, 32, 64);
        float os = __shfl_xor(s1, 32, 64);
        float nm = fmaxf(m1, om);
        float sf = fmaf(s1, ex2(m1 - nm), os * ex2(om - nm));
        if (lane < 32) {
            pm[split * NROWS + rowbase + 32 + lane] = nm;
            ps[split * NROWS + rowbase + 32 + lane] = sf;
        }
    }
}

__global__ void finalize_kernel(const int* __restrict__ gt, const float* __restrict__ wsel,
                                const float* __restrict__ pm, const float* __restrict__ ps,
                                float* __restrict__ bpart) {
    int tid = threadIdx.x;
    int i = blockIdx.x * 256 + tid;
    float mv[MSPLIT];
    float M = -3.0e38f;
    #pragma unroll
    for (int k = 0; k < MSPLIT; ++k) { mv[k] = pm[k * NROWS + i]; M = fmaxf(M, mv[k]); }
    float S = 0.0f;
    #pragma unroll
    for (int k = 0; k < MSPLIT; ++k) S += ps[k * NROWS + i] * ex2(mv[k] - M);
    float lse = (M + __log2f(S)) * LN2;   // back to natural-log domain
    int label = gt[i];
    float per = (label >= 0 && label < NCLS) ? (lse - wsel[i] * (1.0f / 6.0f)) : 0.0f;
    #pragma unroll
    for (int off = 32; off >= 1; off >>= 1) per += __shfl_xor(per, off, 64);
    __shared__ float red[4];
    int lane = tid & 63, wid = tid >> 6;
    if (lane == 0) red[wid] = per;
    __syncthreads();
    if (tid == 0) bpart[blockIdx.x] = red[0] + red[1] + red[2] + red[3];
}

__global__ void sum_kernel(const float* __restrict__ bpart, float* __restrict__ out) {
    int tid = threadIdx.x;
    float v = (tid < 32) ? bpart[tid] : 0.0f;
    #pragma unroll
    for (int off = 32; off >= 1; off >>= 1) v += __shfl_xor(v, off, 64);
    if (tid == 0) out[0] = 0.001f * v;
}

extern "C" void kernel_launch(void* const* d_in, const int* in_sizes, int n_in,
                              void* d_out, int out_size, void* d_ws, size_t ws_size,
                              hipStream_t stream) {
    const int*   gt    = (const int*)d_in[0];
    const float* F     = (const float*)d_in[1];
    const float* Mem   = (const float*)d_in[2];
    const int*   trace = (const int*)d_in[3];
    float* out = (float*)d_out;

    char* w = (char*)d_ws;
    unsigned short* Mb2 = (unsigned short*)w;
    unsigned short* Fb  = (unsigned short*)(w + 10240000);
    float* wsel  = (float*)(w + 14434304);
    float* pm    = (float*)(w + 14467072);
    float* ps    = (float*)(w + 14991360);
    float* bpart = (float*)(w + 15515648);

    prep_kernel<<<dim3(6596), dim3(256), 0, stream>>>(Mem, Mb2, F, Fb, gt, trace, wsel);
    lse_gemm<<<dim3(MSPLIT, NROWS / 256), dim3(256), 0, stream>>>(Fb, Mb2, pm, ps);
    finalize_kernel<<<dim3(NROWS / 256), dim3(256), 0, stream>>>(gt, wsel, pm, ps, bpart);
    sum_kernel<<<dim3(1), dim3(64), 0, stream>>>(bpart, out);
}

// Round 23
// 97.045 us; speedup vs baseline: 1.3084x; 1.0816x over previous
//
#include <hip/hip_runtime.h>
#include <hip/hip_bf16.h>
#include <stdint.h>

// Problem constants
#define NROWS 8192
#define FDIM 256
#define MCOLS 20000
#define NT32 625           // 20000 / 32, exact -> no tail masking
#define MSPLIT 8           // grid 8 x 32 = 256 blocks = 1/CU; split == XCD id
#define NCLS 1000
#define LOG2E 1.44269504088896f
#define LN2   0.69314718055994f

// ws layout (bytes), total ~15.5 MB:
//   Mb2  bf16 memory, MFMA-fragment order : [0, 10240000)
//   Fb   bf16 box*5*log2e (row-major)     : [10240000, 14434304)
//   wsel weighted sel logits              : [14434304, 14467072)
//   pm   partial max [8][N]               : [14467072, 14991360)
//   ps   partial sum [8][N]               : [14991360, 15515648)
//   bpart block partials                  : [15515648, 15515776)
// NOTE: lse_gemm prefetches one tile past the end of Mb2 (harmless read into Fb).

typedef short short8 __attribute__((ext_vector_type(8)));
typedef float f32x16 __attribute__((ext_vector_type(16)));

__device__ __forceinline__ float ex2(float x) {   // raw v_exp_f32 (2^x)
    float r;
    asm("v_exp_f32 %0, %1" : "=v"(r) : "v"(x));
    return r;
}

__device__ __forceinline__ unsigned short f2bf(float x) {
    unsigned u = __float_as_uint(x);
    unsigned r = (u + 0x7FFFu + ((u >> 16) & 1u)) >> 16;   // RNE
    return (unsigned short)r;
}

// max of 16-vector via 3-ary nesting (fuses to v_max3_f32)
__device__ __forceinline__ float vmax16(f32x16 v) {
    float x0 = fmaxf(fmaxf(v[0],  v[1]),  v[2]);
    float x1 = fmaxf(fmaxf(v[3],  v[4]),  v[5]);
    float x2 = fmaxf(fmaxf(v[6],  v[7]),  v[8]);
    float x3 = fmaxf(fmaxf(v[9],  v[10]), v[11]);
    float x4 = fmaxf(fmaxf(v[12], v[13]), v[14]);
    float x5 = fmaxf(fmaxf(x0, x1), x2);
    float x6 = fmaxf(fmaxf(x3, x4), v[15]);
    return fmaxf(x5, x6);
}

// Fused prep + sel:
//   blocks [0,2500)    : Mb2 (fragment-order bf16 memory)
//   blocks [2500,4548) : Fb  (row-major bf16 box * 5*log2e)
//   blocks [4548,6596) : sel (weighted trace logits, fp32-exact)
__global__ void prep_kernel(const float* __restrict__ Mem, unsigned short* __restrict__ Mb2,
                            const float* __restrict__ F, unsigned short* __restrict__ Fb,
                            const int* __restrict__ gt, const int* __restrict__ trace,
                            float* __restrict__ wsel) {
    int b = blockIdx.x;
    if (b < 2500) {
        // Mb2: granule g = (t*16 + kk)*64 + s holds Mem[t*32 + (s&31)][kk*16 + (s>>5)*8 ..+8]
        int g = b * 256 + threadIdx.x;
        int s = g & 63, kk = (g >> 6) & 15, t = g >> 10;
        const float* src = Mem + (size_t)(t * 32 + (s & 31)) * FDIM + kk * 16 + (s >> 5) * 8;
        float4 v0 = ((const float4*)src)[0];
        float4 v1 = ((const float4*)src)[1];
        short8 w;
        w[0] = (short)f2bf(v0.x); w[1] = (short)f2bf(v0.y);
        w[2] = (short)f2bf(v0.z); w[3] = (short)f2bf(v0.w);
        w[4] = (short)f2bf(v1.x); w[5] = (short)f2bf(v1.y);
        w[6] = (short)f2bf(v1.z); w[7] = (short)f2bf(v1.w);
        *(short8*)(Mb2 + (size_t)g * 8) = w;
    } else if (b < 4548) {
        int idx = (b - 2500) * 256 + threadIdx.x;   // 2048 x 256 = 524288 float4s
        float4 v = ((const float4*)F)[idx];
        const float sc = 5.0f * LOG2E;
        ushort4 o;
        o.x = f2bf(v.x * sc); o.y = f2bf(v.y * sc);
        o.z = f2bf(v.z * sc); o.w = f2bf(v.w * sc);
        ((ushort4*)Fb)[idx] = o;
    } else {
        int lane = threadIdx.x & 63, wid = threadIdx.x >> 6;
        int i = (b - 4548) * 4 + wid;
        int label = gt[i];
        float w = 0.0f;
        if (label >= 0 && label < NCLS) {
            float4 fv = ((const float4*)(F + (size_t)i * FDIM))[lane];
            #pragma unroll
            for (int d = 1; d <= 3; ++d) {
                int tr = trace[label * 4 + d];
                float4 mv = ((const float4*)(Mem + (size_t)tr * FDIM))[lane];
                float dot = fv.x*mv.x + fv.y*mv.y + fv.z*mv.z + fv.w*mv.w;
                #pragma unroll
                for (int off = 32; off >= 1; off >>= 1) dot += __shfl_xor(dot, off, 64);
                w += (float)d * dot;
            }
        }
        if (lane == 0) wsel[i] = w * 5.0f;   // 1/T
    }
}

// Fused GEMM + online log2-sum-exp2 partials -- swapped-operand 32x32x16,
// 64 rows/wave, NO LDS / NO BARRIERS (best verified configuration, R18):
// fragment-ordered Mb2 lets each wave global_load_dwordx4 its exact
// B-fragments (1KB contiguous per fragment, coalesced; the block's 4 waves
// read the same tile -> L1 hits; per-XCD 2.5MB chunk L2-resident).
// B double-buffered in registers (b0/b1, static unroll), loads issued a
// FULL TILE ahead in source. Softmax of tile t-1 placed between tiles
// (compiler schedules freely -- pinning and extra chains both measured
// slower: R21 96.7us, R22 92.0us vs this structure's 80.3us).
// waves_per_eu(1,1): full 512-reg budget (B 128 VGPR + al/ah/acc ~192 AGPR).
__global__ __attribute__((amdgpu_flat_work_group_size(256, 256), amdgpu_waves_per_eu(1, 1)))
void lse_gemm(
        const unsigned short* __restrict__ Fb, const unsigned short* __restrict__ Mb2,
        float* __restrict__ pm, float* __restrict__ ps) {
    const int split  = blockIdx.x;   // 0..7 == XCD id (dispatch id % 8)
    const int rowblk = blockIdx.y;   // 0..31
    const int tid  = threadIdx.x;
    const int lane = tid & 63, wid = tid >> 6;
    const int r0 = lane & 31;        // A-row within the 32-row half AND B-col
    const int hi = lane >> 5;        // k-slice half
    const int rowbase = rowblk * 256 + wid * 64;
    const int l16 = lane << 4;       // lane byte offset within a fragment

    // A fragments (Y-operand), two row-halves (al: +r0, ah: +32+r0)
    short8 al[16], ah[16];
    #pragma unroll
    for (int kk = 0; kk < 16; ++kk) {
        al[kk] = *(const short8*)(Fb + (size_t)(rowbase + r0)      * FDIM + kk * 16 + hi * 8);
        ah[kk] = *(const short8*)(Fb + (size_t)(rowbase + 32 + r0) * FDIM + kk * 16 + hi * 8);
    }

    // online state: one row per lane, per half
    float m0 = -3.0e38f, s0 = 0.0f, m1 = -3.0e38f, s1 = 0.0f;
    // softmax pipeline temps
    float nmL, nmH, q0, q1, q2, q3, r0x, r1x, r2x, r3x;
    // double-buffered accumulators + B-fragment register buffers (static idx)
    f32x16 accLA, accHA, accLB, accHB;
    short8 b0[16], b1[16];

    const int t0 = (split * NT32) / MSPLIT;
    const int t1 = ((split + 1) * NT32) / MSPLIT;   // 78-79 tiles per split

    // Load all 16 B-fragments of tile t into register buffer BB (16 x dwordx4,
    // per-lane address = tile base + kk*1024 + lane*16; coalesced 1KB/fragment).
#define LOADB(BB, t)                                                               \
    do {                                                                           \
        const char* srcT_ = (const char*)Mb2 + (size_t)(t) * 16384 + l16;          \
        _Pragma("unroll")                                                          \
        for (int kk = 0; kk < 16; ++kk)                                            \
            BB[kk] = *(const short8*)(srcT_ + kk * 1024);                          \
    } while (0)

#define MFMA_K(BB, CUR, KK)                                                        \
    {                                                                              \
        accL##CUR = __builtin_amdgcn_mfma_f32_32x32x16_bf16(BB[KK], al[KK], accL##CUR, 0, 0, 0); \
        accH##CUR = __builtin_amdgcn_mfma_f32_32x32x16_bf16(BB[KK], ah[KK], accH##CUR, 0, 0, 0); \
    }

#define SM_P0(P)                                                                   \
    nmL = fmaxf(vmax16(accL##P), m0); nmH = fmaxf(vmax16(accH##P), m1);            \
    q0 = q1 = q2 = q3 = 0.f; r0x = r1x = r2x = r3x = 0.f;

#define SM_P1(P)                                                                   \
    q0 += ex2(accL##P[0] - nmL); q1 += ex2(accL##P[1] - nmL);                      \
    q2 += ex2(accL##P[2] - nmL); q3 += ex2(accL##P[3] - nmL);                      \
    q0 += ex2(accL##P[4] - nmL); q1 += ex2(accL##P[5] - nmL);                      \
    q2 += ex2(accL##P[6] - nmL); q3 += ex2(accL##P[7] - nmL);

#define SM_P2(P)                                                                   \
    q0 += ex2(accL##P[8]  - nmL); q1 += ex2(accL##P[9]  - nmL);                    \
    q2 += ex2(accL##P[10] - nmL); q3 += ex2(accL##P[11] - nmL);                    \
    q0 += ex2(accL##P[12] - nmL); q1 += ex2(accL##P[13] - nmL);                    \
    q2 += ex2(accL##P[14] - nmL); q3 += ex2(accL##P[15] - nmL);                    \
    s0 = fmaf(s0, ex2(m0 - nmL), (q0 + q1) + (q2 + q3)); m0 = nmL;

#define SM_P3(P)                                                                   \
    r0x += ex2(accH##P[0]  - nmH); r1x += ex2(accH##P[1]  - nmH);                  \
    r2x += ex2(accH##P[2]  - nmH); r3x += ex2(accH##P[3]  - nmH);                  \
    r0x += ex2(accH##P[4]  - nmH); r1x += ex2(accH##P[5]  - nmH);                  \
    r2x += ex2(accH##P[6]  - nmH); r3x += ex2(accH##P[7]  - nmH);                  \
    r0x += ex2(accH##P[8]  - nmH); r1x += ex2(accH##P[9]  - nmH);                  \
    r2x += ex2(accH##P[10] - nmH); r3x += ex2(accH##P[11] - nmH);                  \
    r0x += ex2(accH##P[12] - nmH); r1x += ex2(accH##P[13] - nmH);                  \
    r2x += ex2(accH##P[14] - nmH); r3x += ex2(accH##P[15] - nmH);                  \
    s1 = fmaf(s1, ex2(m1 - nmH), (r0x + r1x) + (r2x + r3x)); m1 = nmH;

    // MFMA(tile in BB -> CUR) with SM(prev tile PRV) interleaved in 4 chunks.
#define PIPE(BB, CUR, PRV)                                                         \
    do {                                                                           \
        f32x16 z_ = {0,0,0,0,0,0,0,0,0,0,0,0,0,0,0,0};                             \
        accL##CUR = z_; accH##CUR = z_;                                            \
        _Pragma("unroll") for (int kk = 0;  kk < 4;  ++kk) MFMA_K(BB, CUR, kk)     \
        SM_P0(PRV)                                                                 \
        _Pragma("unroll") for (int kk = 4;  kk < 8;  ++kk) MFMA_K(BB, CUR, kk)     \
        SM_P1(PRV)                                                                 \
        _Pragma("unroll") for (int kk = 8;  kk < 12; ++kk) MFMA_K(BB, CUR, kk)     \
        SM_P2(PRV)                                                                 \
        _Pragma("unroll") for (int kk = 12; kk < 16; ++kk) MFMA_K(BB, CUR, kk)     \
        SM_P3(PRV)                                                                 \
    } while (0)

#define MFMA_ONLY(BB, CUR)                                                         \
    do {                                                                           \
        f32x16 z_ = {0,0,0,0,0,0,0,0,0,0,0,0,0,0,0,0};                             \
        accL##CUR = z_; accH##CUR = z_;                                            \
        _Pragma("unroll") for (int kk = 0; kk < 16; ++kk) MFMA_K(BB, CUR, kk)      \
    } while (0)

#define SM_FULL(P) do { SM_P0(P) SM_P1(P) SM_P2(P) SM_P3(P) } while (0)

    // Prologue: fill both B buffers, compute tile t0 -> accA.
    LOADB(b0, t0);
    LOADB(b1, t0 + 1);         // nt >= 78, always exists
    MFMA_ONLY(b0, A);

    int t = t0 + 1;            // tile t is in b1 at loop head
    while (t + 1 < t1) {
        LOADB(b0, t + 1);      // prefetch next tile into the freed buffer
        PIPE(b1, B, A);        // tile t -> accB; softmax(tile t-1 = accA)
        if (t + 2 < t1) LOADB(b1, t + 2);
        PIPE(b0, A, B);        // tile t+1 -> accA; softmax(tile t = accB)
        t += 2;
    }
    if (t < t1) {              // one tile left, resident in b1
        PIPE(b1, B, A);
        SM_FULL(B);
    } else {
        SM_FULL(A);
    }

#undef SM_FULL
#undef MFMA_ONLY
#undef PIPE
#undef SM_P3
#undef SM_P2
#undef SM_P1
#undef SM_P0
#undef MFMA_K
#undef LOADB

    // Combine the two k-slice halves: lane l and l^32 hold the same row's two
    // 16-col subsets (for both row-halves).
    {
        float om = __shfl_xor(m0, 32, 64);
        float os = __shfl_xor(s0, 32, 64);
        float nm = fmaxf(m0, om);
        float sf = fmaf(s0, ex2(m0 - nm), os * ex2(om - nm));
        if (lane < 32) {
            pm[split * NROWS + rowbase + lane] = nm;
            ps[split * NROWS + rowbase + lane] = sf;
        }
    }
    {
        float om = __shfl_xor(m1, 32, 64);
        float os = __shfl_xor(s1, 32, 64);
        float nm = fmaxf(m1, om);
        float sf = fmaf(s1, ex2(m1 - nm), os * ex2(om - nm));
        if (lane < 32) {
            pm[split * NROWS + rowbase + 32 + lane] = nm;
            ps[split * NROWS + rowbase + 32 + lane] = sf;
        }
    }
}

__global__ void finalize_kernel(const int* __restrict__ gt, const float* __restrict__ wsel,
                                const float* __restrict__ pm, const float* __restrict__ ps,
                                float* __restrict__ bpart) {
    int tid = threadIdx.x;
    int i = blockIdx.x * 256 + tid;
    float mv[MSPLIT];
    float M = -3.0e38f;
    #pragma unroll
    for (int k = 0; k < MSPLIT; ++k) { mv[k] = pm[k * NROWS + i]; M = fmaxf(M, mv[k]); }
    float S = 0.0f;
    #pragma unroll
    for (int k = 0; k < MSPLIT; ++k) S += ps[k * NROWS + i] * ex2(mv[k] - M);
    float lse = (M + __log2f(S)) * LN2;   // back to natural-log domain
    int label = gt[i];
    float per = (label >= 0 && label < NCLS) ? (lse - wsel[i] * (1.0f / 6.0f)) : 0.0f;
    #pragma unroll
    for (int off = 32; off >= 1; off >>= 1) per += __shfl_xor(per, off, 64);
    __shared__ float red[4];
    int lane = tid & 63, wid = tid >> 6;
    if (lane == 0) red[wid] = per;
    __syncthreads();
    if (tid == 0) bpart[blockIdx.x] = red[0] + red[1] + red[2] + red[3];
}

__global__ void sum_kernel(const float* __restrict__ bpart, float* __restrict__ out) {
    int tid = threadIdx.x;
    float v = (tid < 32) ? bpart[tid] : 0.0f;
    #pragma unroll
    for (int off = 32; off >= 1; off >>= 1) v += __shfl_xor(v, off, 64);
    if (tid == 0) out[0] = 0.001f * v;
}

extern "C" void kernel_launch(void* const* d_in, const int* in_sizes, int n_in,
                              void* d_out, int out_size, void* d_ws, size_t ws_size,
                              hipStream_t stream) {
    const int*   gt    = (const int*)d_in[0];
    const float* F     = (const float*)d_in[1];
    const float* Mem   = (const float*)d_in[2];
    const int*   trace = (const int*)d_in[3];
    float* out = (float*)d_out;

    char* w = (char*)d_ws;
    unsigned short* Mb2 = (unsigned short*)w;
    unsigned short* Fb  = (unsigned short*)(w + 10240000);
    float* wsel  = (float*)(w + 14434304);
    float* pm    = (float*)(w + 14467072);
    float* ps    = (float*)(w + 14991360);
    float* bpart = (float*)(w + 15515648);

    prep_kernel<<<dim3(6596), dim3(256), 0, stream>>>(Mem, Mb2, F, Fb, gt, trace, wsel);
    lse_gemm<<<dim3(MSPLIT, NROWS / 256), dim3(256), 0, stream>>>(Fb, Mb2, pm, ps);
    finalize_kernel<<<dim3(NROWS / 256), dim3(256), 0, stream>>>(gt, wsel, pm, ps, bpart);
    sum_kernel<<<dim3(1), dim3(64), 0, stream>>>(bpart, out);
}